// Round 7
// baseline (19206.648 us; speedup 1.0000x reference)
//
#include <hip/hip_runtime.h>
#include <math.h>

#define NN 20000
#define NE 240000
#define NL 480000
#define NB 128

static inline int cdiv(int a, int b){ return (a+b-1)/b; }

// ---------------------------------------------------------------------------
// Workspace as a device-global (BSS) array: the harness's d_ws size is
// unknown (two aborts at 625MB and 380MB footprints are consistent with
// d_ws being tiny). Globals are allocated at module load -> graph-capture
// safe, no dependency on ws_size. Every sub-buffer is fully initialized
// within kernel_launch before use (no cross-call state).
//
// layout (floats):
//  h    @ 0          [NN,128]   2,560,000
//  e    @ 2,560,000  [NE,128]  30,720,000
//  a    @ 33,280,000 [NL,32]   15,360,000
//  z    @ 48,640,000 [NE,128]  30,720,000   (lc z=[NL,32] fits)
//  sgp  @ 79,360,000 [NE,32]    7,680,000   (ac sgp=[NN,128] fits)
//  dgp  @ 87,040,000 [NE,32]    7,680,000
//  smp  @ 94,720,000 [NE,128]  30,720,000   (ac smp=[NN,128] fits)
//  agg  @125,440,000 [NE,128]  30,720,000   (ac agg=[NN,128] fits)
//  stats@156,160,000 [1024]
//  pooled@156,161,024 [NB*128+NB]
// total 156,177,537 floats ~= 625 MB
// ---------------------------------------------------------------------------
#define WS_TOTAL 156180000ull
__device__ __align__(16) float g_ws[WS_TOTAL];

__device__ __forceinline__ float dsigm(float x){ return 1.0f/(1.0f+__expf(-x)); }
__device__ __forceinline__ float dsilu(float x){ return x/(1.0f+__expf(-x)); }

struct f8 { float v[8]; };
__device__ __forceinline__ f8 load8(const float* __restrict__ p){
    f8 r;
    float4 a = *(const float4*)p;
    float4 b = *(const float4*)(p+4);
    r.v[0]=a.x; r.v[1]=a.y; r.v[2]=a.z; r.v[3]=a.w;
    r.v[4]=b.x; r.v[5]=b.y; r.v[6]=b.z; r.v[7]=b.w;
    return r;
}

// ---------------------------------------------------------------------------
// Plain GEMM: out[R,C] = in[R,K] @ W[K,C] + b.  K%4==0, rows 16B-aligned.
// Weight in LDS transposed [c][k] with XOR swizzle on the k4 group.
// Thread: 4 rows x 8 cols register tile.
// ---------------------------------------------------------------------------
template<int K, int C>
__global__ __launch_bounds__(256) void gemm_f4_kernel(const float* __restrict__ in,
    const float* __restrict__ W, const float* __restrict__ bias,
    float* __restrict__ out, int R)
{
    constexpr int CG = C/8;
    constexpr int RG = 256/CG;
    constexpr int ROWS = RG*4;
    __shared__ float wt[C*K];
    for (int i = threadIdx.x; i < K*C; i += 256){
        int k = i / C, c = i % C;
        wt[c*K + ((((k>>2) ^ ((c>>3)&7))<<2)) + (k&3)] = W[i];
    }
    __syncthreads();
    const int cg = threadIdx.x % CG;
    const int rg = threadIdx.x / CG;
    const int c0 = cg*8;
    const int r0 = blockIdx.x*ROWS + rg*4;
    float acc[4][8];
    #pragma unroll
    for (int i=0;i<4;++i){
        #pragma unroll
        for (int u=0;u<8;++u) acc[i][u]=0.f;
    }
    #pragma unroll 2
    for (int k4=0;k4<K/4;++k4){
        float4 av[4];
        #pragma unroll
        for (int i=0;i<4;++i){
            int r=r0+i;
            av[i] = (r<R) ? *(const float4*)(in + (size_t)r*K + k4*4) : make_float4(0.f,0.f,0.f,0.f);
        }
        #pragma unroll
        for (int u=0;u<8;++u){
            int c=c0+u;
            float4 wv = *(const float4*)(wt + c*K + ((k4 ^ ((c>>3)&7))<<2));
            #pragma unroll
            for (int i=0;i<4;++i)
                acc[i][u] = fmaf(av[i].w, wv.w, fmaf(av[i].z, wv.z, fmaf(av[i].y, wv.y, fmaf(av[i].x, wv.x, acc[i][u]))));
        }
    }
    float b[8];
    #pragma unroll
    for (int u=0;u<8;++u) b[u]=bias[c0+u];
    #pragma unroll
    for (int i=0;i<4;++i){
        int r=r0+i;
        if (r<R){
            float4 o0 = make_float4(acc[i][0]+b[0], acc[i][1]+b[1], acc[i][2]+b[2], acc[i][3]+b[3]);
            float4 o1 = make_float4(acc[i][4]+b[4], acc[i][5]+b[5], acc[i][6]+b[6], acc[i][7]+b[7]);
            *(float4*)(out + (size_t)r*C + c0)     = o0;
            *(float4*)(out + (size_t)r*C + c0 + 4) = o1;
        }
    }
}

// ---------------------------------------------------------------------------
// Scalar-K GEMM for unaligned embedding GEMMs (K=92,41).
// ---------------------------------------------------------------------------
template<int K, int C>
__global__ __launch_bounds__(256) void gemm_sc_kernel(const float* __restrict__ in,
    const float* __restrict__ W, const float* __restrict__ bias,
    float* __restrict__ out, int R)
{
    __shared__ float wl[K*C];
    for (int i=threadIdx.x;i<K*C;i+=256) wl[i]=W[i];
    __syncthreads();
    const int c  = threadIdx.x & (C-1);
    const int rl = threadIdx.x / C;
    constexpr int RPB = 256/C;
    float bv = bias[c];
    for (int r = blockIdx.x*RPB + rl; r < R; r += gridDim.x*RPB){
        const float* irow = in + (size_t)r*K;
        float acc = bv;
        #pragma unroll 4
        for (int k=0;k<K;++k) acc = fmaf(irow[k], wl[k*C+c], acc);
        out[(size_t)r*C + c] = acc;
    }
}

// a[l][c] = line_attr[l] * W_ng[c] + b_ng[c]   (ANGLE_D==1)
__global__ __launch_bounds__(256) void embed_a_kernel(const float* __restrict__ la,
    const float* __restrict__ w, const float* __restrict__ b, float* __restrict__ a)
{
    __shared__ float sw[32], sb[32];
    if (threadIdx.x < 32){ sw[threadIdx.x]=w[threadIdx.x]; sb[threadIdx.x]=b[threadIdx.x]; }
    __syncthreads();
    const int total = NL*8;
    for (int i = blockIdx.x*256+threadIdx.x; i < total; i += gridDim.x*256){
        int l = i >> 3, c0 = (i&7)*4;
        float lv = la[l];
        float4 o = make_float4(fmaf(lv,sw[c0],sb[c0]),   fmaf(lv,sw[c0+1],sb[c0+1]),
                               fmaf(lv,sw[c0+2],sb[c0+2]), fmaf(lv,sw[c0+3],sb[c0+3]));
        *(float4*)(a + (size_t)i*4) = o;
    }
}

// ---------------------------------------------------------------------------
// Edge phase 1: gate = sigmoid(sgp[row] + dgp[col] + ea@eg_w + eg_b)
//               z    = silu(gate * ea); accumulate per-channel sum/sumsq.
// Stats reduced via LDS (aliasing wt after the k-loop) then global atomics.
// ---------------------------------------------------------------------------
template<int ED>
__global__ __launch_bounds__(256) void egc_gate_kernel(
    const float* __restrict__ ea,
    const float* __restrict__ sgp, const float* __restrict__ dgp,
    const int* __restrict__ row_idx, const int* __restrict__ col_idx,
    const float* __restrict__ eg_w, const float* __restrict__ eg_b,
    float* __restrict__ z, float* __restrict__ stat_sum, float* __restrict__ stat_sq,
    int R)
{
    constexpr int K = ED, C = ED;
    constexpr int CG = C/8;
    constexpr int RG = 256/CG;
    constexpr int ROWS = RG*4;
    __shared__ float wt[C*K];
    for (int i = threadIdx.x; i < K*C; i += 256){
        int k = i / C, c = i % C;
        wt[c*K + ((((k>>2) ^ ((c>>3)&7))<<2)) + (k&3)] = eg_w[i];
    }
    __syncthreads();
    const int cg = threadIdx.x % CG;
    const int rg = threadIdx.x / CG;
    const int c0 = cg*8;
    const int r0 = blockIdx.x*ROWS + rg*4;
    float acc[4][8];
    #pragma unroll
    for (int i=0;i<4;++i){
        #pragma unroll
        for (int u=0;u<8;++u) acc[i][u]=0.f;
    }
    #pragma unroll 2
    for (int k4=0;k4<K/4;++k4){
        float4 av[4];
        #pragma unroll
        for (int i=0;i<4;++i){
            int r=r0+i;
            av[i] = (r<R) ? *(const float4*)(ea + (size_t)r*K + k4*4) : make_float4(0.f,0.f,0.f,0.f);
        }
        #pragma unroll
        for (int u=0;u<8;++u){
            int c=c0+u;
            float4 wv = *(const float4*)(wt + c*K + ((k4 ^ ((c>>3)&7))<<2));
            #pragma unroll
            for (int i=0;i<4;++i)
                acc[i][u] = fmaf(av[i].w, wv.w, fmaf(av[i].z, wv.z, fmaf(av[i].y, wv.y, fmaf(av[i].x, wv.x, acc[i][u]))));
        }
    }
    float eb[8];
    #pragma unroll
    for (int u=0;u<8;++u) eb[u] = eg_b[c0+u];
    float lsum[8], lsq[8];
    #pragma unroll
    for (int u=0;u<8;++u){ lsum[u]=0.f; lsq[u]=0.f; }
    #pragma unroll
    for (int i=0;i<4;++i){
        int r = r0+i;
        if (r < R){
            int rj = row_idx[r], cj = col_idx[r];
            f8 sg = load8(sgp + (size_t)rj*C + c0);
            f8 dg = load8(dgp + (size_t)cj*C + c0);
            f8 ev = load8(ea  + (size_t)r*C + c0);
            float zr[8];
            #pragma unroll
            for (int u=0;u<8;++u){
                float gate = dsigm(acc[i][u] + sg.v[u] + dg.v[u] + eb[u]);
                float t = gate * ev.v[u];
                float zs = dsilu(t);
                zr[u] = zs;
                lsum[u] += zs; lsq[u] += zs*zs;
            }
            *(float4*)(z + (size_t)r*C + c0)   = make_float4(zr[0],zr[1],zr[2],zr[3]);
            *(float4*)(z + (size_t)r*C + c0+4) = make_float4(zr[4],zr[5],zr[6],zr[7]);
        }
    }
    __syncthreads();                 // all wt reads complete -> reuse as stats
    float* ssum = wt;
    float* ssq  = wt + C;
    if (threadIdx.x < 2*C) wt[threadIdx.x] = 0.f;
    __syncthreads();
    #pragma unroll
    for (int u=0;u<8;++u){ atomicAdd(&ssum[c0+u], lsum[u]); atomicAdd(&ssq[c0+u], lsq[u]); }
    __syncthreads();
    if (threadIdx.x < C){
        atomicAdd(&stat_sum[threadIdx.x], ssum[threadIdx.x]);
        atomicAdd(&stat_sq[threadIdx.x],  ssq[threadIdx.x]);
    }
}

// mean/var -> affine A,B so that BN(v) = v*A + B
__global__ void bn_finalize_kernel(const float* __restrict__ sum, const float* __restrict__ sq,
    const float* __restrict__ gamma, const float* __restrict__ beta,
    float* __restrict__ A, float* __restrict__ B, float inv_n, int C)
{
    int c = threadIdx.x;
    if (c < C){
        float mu  = sum[c]*inv_n;
        float var = sq[c]*inv_n - mu*mu;
        float rs  = rsqrtf(var + 1e-5f);
        float a   = gamma[c]*rs;
        A[c] = a;
        B[c] = fmaf(-mu, a, beta[c]);
    }
}

// ---------------------------------------------------------------------------
// Edge phase 2: ea_new = z*A+B (BN affine); ea += ea_new (residual, in place);
// msg = smp[row] + ea_new@em_w + em_b; atomicAdd into agg[col].
// ---------------------------------------------------------------------------
template<int ED, int ND>
__global__ __launch_bounds__(256) void egc_msg_kernel(
    const float* __restrict__ z, float* __restrict__ ea,
    const float* __restrict__ bnA, const float* __restrict__ bnB,
    const float* __restrict__ smp,
    const int* __restrict__ row_idx, const int* __restrict__ col_idx,
    const float* __restrict__ em_w, const float* __restrict__ em_b,
    float* __restrict__ agg, int R)
{
    constexpr int K = ED, C = ND;
    constexpr int CG = C/8;
    constexpr int RG = 256/CG;
    constexpr int ROWS = RG*4;
    __shared__ float wt[C*K];
    for (int i=threadIdx.x;i<K*C;i+=256){
        int k=i/C, c=i%C;
        wt[c*K + ((((k>>2) ^ ((c>>3)&7))<<2)) + (k&3)] = em_w[i];
    }
    __syncthreads();
    const int cg = threadIdx.x % CG;
    const int rg = threadIdx.x / CG;
    const int c0 = cg*8;
    const int r0 = blockIdx.x*ROWS + rg*4;
    float acc[4][8];
    #pragma unroll
    for (int i=0;i<4;++i){
        #pragma unroll
        for (int u=0;u<8;++u) acc[i][u]=0.f;
    }
    #pragma unroll 2
    for (int k4=0;k4<K/4;++k4){
        const float4 Af = *(const float4*)(bnA + k4*4);
        const float4 Bf = *(const float4*)(bnB + k4*4);
        float4 av[4];
        #pragma unroll
        for (int i=0;i<4;++i){
            int r=r0+i;
            if (r<R){
                float4 zv = *(const float4*)(z + (size_t)r*K + k4*4);
                float4 t;
                t.x = fmaf(zv.x, Af.x, Bf.x);
                t.y = fmaf(zv.y, Af.y, Bf.y);
                t.z = fmaf(zv.z, Af.z, Bf.z);
                t.w = fmaf(zv.w, Af.w, Bf.w);
                av[i]=t;
                if (cg==0){   // residual: ea += ea_new (one writer per row)
                    float4 evv = *(const float4*)(ea + (size_t)r*K + k4*4);
                    evv.x+=t.x; evv.y+=t.y; evv.z+=t.z; evv.w+=t.w;
                    *(float4*)(ea + (size_t)r*K + k4*4) = evv;
                }
            } else av[i]=make_float4(0.f,0.f,0.f,0.f);
        }
        #pragma unroll
        for (int u=0;u<8;++u){
            int c=c0+u;
            float4 wv = *(const float4*)(wt + c*K + ((k4 ^ ((c>>3)&7))<<2));
            #pragma unroll
            for (int i=0;i<4;++i)
                acc[i][u] = fmaf(av[i].w, wv.w, fmaf(av[i].z, wv.z, fmaf(av[i].y, wv.y, fmaf(av[i].x, wv.x, acc[i][u]))));
        }
    }
    float mb[8];
    #pragma unroll
    for (int u=0;u<8;++u) mb[u]=em_b[c0+u];
    #pragma unroll
    for (int i=0;i<4;++i){
        int r=r0+i;
        if (r<R){
            int rj=row_idx[r], cj=col_idx[r];
            f8 sm = load8(smp + (size_t)rj*C + c0);
            #pragma unroll
            for (int u=0;u<8;++u){
                float m = acc[i][u] + mb[u] + sm.v[u];
                atomicAdd(&agg[(size_t)cj*C + c0 + u], m);
            }
        }
    }
}

// stats of silu(agg) over rows; agg is [R,128]
__global__ __launch_bounds__(256) void node_stats_kernel(const float* __restrict__ agg,
    float* __restrict__ stat_sum, float* __restrict__ stat_sq, int R)
{
    __shared__ float ssum[128], ssq[128];
    if (threadIdx.x < 128){ ssum[threadIdx.x]=0.f; ssq[threadIdx.x]=0.f; }
    __syncthreads();
    const int cg = threadIdx.x & 31, rg = threadIdx.x >> 5;
    const int c0 = cg*4;
    float ls[4]={0.f,0.f,0.f,0.f}, lq[4]={0.f,0.f,0.f,0.f};
    for (int r = blockIdx.x*8 + rg; r < R; r += gridDim.x*8){
        float4 v = *(const float4*)(agg + (size_t)r*128 + c0);
        float s;
        s = dsilu(v.x); ls[0]+=s; lq[0]+=s*s;
        s = dsilu(v.y); ls[1]+=s; lq[1]+=s*s;
        s = dsilu(v.z); ls[2]+=s; lq[2]+=s*s;
        s = dsilu(v.w); ls[3]+=s; lq[3]+=s*s;
    }
    #pragma unroll
    for (int j=0;j<4;++j){ atomicAdd(&ssum[c0+j], ls[j]); atomicAdd(&ssq[c0+j], lq[j]); }
    __syncthreads();
    if (threadIdx.x < 128){
        atomicAdd(&stat_sum[threadIdx.x], ssum[threadIdx.x]);
        atomicAdd(&stat_sq[threadIdx.x],  ssq[threadIdx.x]);
    }
}

// x += silu(agg)*A + B
__global__ __launch_bounds__(256) void node_apply_kernel(float* __restrict__ x,
    const float* __restrict__ agg,
    const float* __restrict__ A, const float* __restrict__ B, int total4)
{
    __shared__ float sA[128], sB[128];
    if (threadIdx.x<128){ sA[threadIdx.x]=A[threadIdx.x]; sB[threadIdx.x]=B[threadIdx.x]; }
    __syncthreads();
    for (int i = blockIdx.x*256+threadIdx.x; i < total4; i += gridDim.x*256){
        int c0 = (i*4) & 127;
        float4 v  = *(const float4*)(agg + (size_t)i*4);
        float4 xv = *(const float4*)(x   + (size_t)i*4);
        xv.x += fmaf(dsilu(v.x), sA[c0],   sB[c0]);
        xv.y += fmaf(dsilu(v.y), sA[c0+1], sB[c0+1]);
        xv.z += fmaf(dsilu(v.z), sA[c0+2], sB[c0+2]);
        xv.w += fmaf(dsilu(v.w), sA[c0+3], sB[c0+3]);
        *(float4*)(x + (size_t)i*4) = xv;
    }
}

__global__ __launch_bounds__(256) void pool_kernel(const float* __restrict__ h,
    const int* __restrict__ batch, float* __restrict__ pooled, float* __restrict__ cnt)
{
    const int total = NN*32;
    for (int i = blockIdx.x*256+threadIdx.x; i < total; i += gridDim.x*256){
        int n = i >> 5, c0 = (i&31)*4;
        int b = batch[n];
        float4 v = *(const float4*)(h + (size_t)n*128 + c0);
        atomicAdd(&pooled[b*128+c0],   v.x);
        atomicAdd(&pooled[b*128+c0+1], v.y);
        atomicAdd(&pooled[b*128+c0+2], v.z);
        atomicAdd(&pooled[b*128+c0+3], v.w);
        if (c0==0) atomicAdd(&cnt[b], 1.f);
    }
}

__global__ __launch_bounds__(128) void mlp_kernel(const float* __restrict__ pooled,
    const float* __restrict__ cnt,
    const float* __restrict__ W1, const float* __restrict__ b1,
    const float* __restrict__ W2, const float* __restrict__ b2,
    const float* __restrict__ W3, const float* __restrict__ b3,
    float* __restrict__ out)
{
    __shared__ float p[128], o1[128], red[64];
    int g = blockIdx.x, t = threadIdx.x;
    float c = fmaxf(cnt[g], 1.0f);
    p[t] = pooled[g*128+t] / c;
    __syncthreads();
    float acc = b1[t];
    for (int k=0;k<128;++k) acc = fmaf(p[k], W1[k*128+t], acc);
    o1[t] = dsilu(acc);
    __syncthreads();
    if (t < 64){
        float a2 = b2[t];
        for (int k=0;k<128;++k) a2 = fmaf(o1[k], W2[k*64+t], a2);
        red[t] = dsilu(a2) * W3[t];
    }
    __syncthreads();
    for (int s2=32; s2>0; s2>>=1){
        if (t < s2) red[t] += red[t+s2];
        __syncthreads();
    }
    if (t==0) out[g] = red[0] + b3[0];
}

// ---------------------------------------------------------------------------
extern "C" void kernel_launch(void* const* d_in, const int* in_sizes, int n_in,
                              void* d_out, int out_size, void* d_ws, size_t ws_size,
                              hipStream_t stream)
{
    (void)in_sizes; (void)n_in; (void)out_size; (void)d_ws; (void)ws_size;

    const float* x_in      = (const float*)d_in[0];
    const int*   edge_index= (const int*)d_in[1];
    const float* edge_attr = (const float*)d_in[2];
    const int*   line_index= (const int*)d_in[3];
    const float* line_attr = (const float*)d_in[4];
    const int*   batch     = (const int*)d_in[5];
    const float* W_ae=(const float*)d_in[6];  const float* b_ae=(const float*)d_in[7];
    const float* W_ee=(const float*)d_in[8];  const float* b_ee=(const float*)d_in[9];
    const float* W_ng=(const float*)d_in[10]; const float* b_ng=(const float*)d_in[11];
    const float* W1=(const float*)d_in[12];   const float* b1=(const float*)d_in[13];
    const float* W2=(const float*)d_in[14];   const float* b2=(const float*)d_in[15];
    const float* W3=(const float*)d_in[16];   const float* b3=(const float*)d_in[17];
    const float* P[28];
    for (int i=0;i<28;++i) P[i] = (const float*)d_in[18+i];
    const float* const* LCQ = P;        // lc_* in _P order
    const float* const* ACQ = P + 14;   // ac_*

    // ---- workspace from device-global BSS (not d_ws)
    float* ws = nullptr;
    hipGetSymbolAddress((void**)&ws, HIP_SYMBOL(g_ws));
    float* h     = ws;                        // [NN,128]
    float* e     = ws + 2560000;              // [NE,128]
    float* a     = ws + 33280000;             // [NL,32]
    float* z     = ws + 48640000;             // [NE,128] (>= NL*32)
    float* sgp   = ws + 79360000;             // [NE,32]  (>= NN*128)
    float* dgp   = ws + 87040000;             // [NE,32]
    float* smp   = ws + 94720000;             // [NE,128] (>= NN*128)
    float* agg   = ws + 125440000;            // [NE,128] (>= NN*128)
    float* stats = ws + 156160000;            // 1024
    float* pooled= stats + 1024;              // [NB,128]+NB
    float* cnt   = pooled + NB*128;

    const int* row  = edge_index;
    const int* col  = edge_index + NE;
    const int* lrow = line_index;
    const int* lcol = line_index + NL;

    // ---- embeddings
    gemm_sc_kernel<92,128><<<4096,256,0,stream>>>(x_in,      W_ae, b_ae, h, NN);
    gemm_sc_kernel<41,128><<<8192,256,0,stream>>>(edge_attr, W_ee, b_ee, e, NE);
    embed_a_kernel<<<2048,256,0,stream>>>(line_attr, W_ng, b_ng, a);

    auto run_egc = [&](float* xb, int Rx, float* eab, int Re, bool big,
                       const int* ridx, const int* cidx,
                       const float* const* q, int li){
        const float* sg_w = q[0]  + (size_t)li*(big?16384:4096);
        const float* sg_b = q[1]  + li*(big?128:32);
        const float* dg_w = q[2]  + (size_t)li*(big?16384:4096);
        const float* dg_b = q[3]  + li*(big?128:32);
        const float* eg_w = q[4]  + (size_t)li*(big?16384:1024);
        const float* eg_b = q[5]  + li*(big?128:32);
        const float* bne_g= q[6]  + li*(big?128:32);
        const float* bne_b= q[7]  + li*(big?128:32);
        const float* sm_w = q[8]  + (size_t)li*16384;
        const float* sm_b = q[9]  + li*128;
        const float* em_w = q[10] + (size_t)li*(big?16384:4096);
        const float* em_b = q[11] + li*128;
        const float* bnn_g= q[12] + li*128;
        const float* bnn_b= q[13] + li*128;

        // node projections
        if (big){
            gemm_f4_kernel<128,128><<<cdiv(Rx,64),256,0,stream>>>(xb, sg_w, sg_b, sgp, Rx);
            gemm_f4_kernel<128,128><<<cdiv(Rx,64),256,0,stream>>>(xb, dg_w, dg_b, dgp, Rx);
        } else {
            gemm_f4_kernel<128,32><<<cdiv(Rx,256),256,0,stream>>>(xb, sg_w, sg_b, sgp, Rx);
            gemm_f4_kernel<128,32><<<cdiv(Rx,256),256,0,stream>>>(xb, dg_w, dg_b, dgp, Rx);
        }
        gemm_f4_kernel<128,128><<<cdiv(Rx,64),256,0,stream>>>(xb, sm_w, sm_b, smp, Rx);

        hipMemsetAsync(stats, 0, 1024*sizeof(float), stream);
        if (big)
            egc_gate_kernel<128><<<cdiv(Re,64),256,0,stream>>>(eab, sgp, dgp, ridx, cidx,
                eg_w, eg_b, z, stats, stats+128, Re);
        else
            egc_gate_kernel<32><<<cdiv(Re,256),256,0,stream>>>(eab, sgp, dgp, ridx, cidx,
                eg_w, eg_b, z, stats, stats+128, Re);
        bn_finalize_kernel<<<1,128,0,stream>>>(stats, stats+128, bne_g, bne_b,
            stats+256, stats+384, 1.0f/(float)Re, big?128:32);

        hipMemsetAsync(agg, 0, (size_t)Rx*128*sizeof(float), stream);
        if (big)
            egc_msg_kernel<128,128><<<cdiv(Re,64),256,0,stream>>>(z, eab, stats+256, stats+384,
                smp, ridx, cidx, em_w, em_b, agg, Re);
        else
            egc_msg_kernel<32,128><<<cdiv(Re,64),256,0,stream>>>(z, eab, stats+256, stats+384,
                smp, ridx, cidx, em_w, em_b, agg, Re);

        node_stats_kernel<<<1024,256,0,stream>>>(agg, stats+512, stats+640, Rx);
        bn_finalize_kernel<<<1,128,0,stream>>>(stats+512, stats+640, bnn_g, bnn_b,
            stats+768, stats+896, 1.0f/(float)Rx, 128);
        node_apply_kernel<<<2048,256,0,stream>>>(xb, agg, stats+768, stats+896, Rx*32);
    };

    for (int i=0;i<3;++i){
        run_egc(e, NE, a, NL, false, lrow, lcol, LCQ, i);   // line-graph conv
        run_egc(h, NN, e, NE, true,  row,  col,  ACQ, i);   // atom-graph conv
    }
    for (int i=3;i<6;++i)
        run_egc(h, NN, e, NE, true, row, col, ACQ, i);      // GCN layers

    // ---- pooling + MLP head
    hipMemsetAsync(pooled, 0, ((size_t)NB*128 + NB)*sizeof(float), stream);
    pool_kernel<<<1024,256,0,stream>>>(h, batch, pooled, cnt);
    mlp_kernel<<<NB,128,0,stream>>>(pooled, cnt, W1,b1,W2,b2,W3,b3, (float*)d_out);
}

// Round 9
// 11242.119 us; speedup vs baseline: 1.7085x; 1.7085x over previous
//
#include <hip/hip_runtime.h>
#include <math.h>

#define NN 20000
#define NE 240000
#define NL 480000
#define NB 128

static inline int cdiv(int a, int b){ return (a+b-1)/b; }

// ---------------------------------------------------------------------------
// Workspace in device-global BSS (d_ws size unknown; BSS is load-time alloc,
// graph-capture safe). Every sub-buffer fully (re)initialized per call.
//
// float layout:
//  h    @ 0            [NN,128]   2,560,000
//  e    @ 2,560,000    [NE,128]  30,720,000
//  a    @ 33,280,000   [NL,32]   15,360,000
//  z    @ 48,640,000   [NE,128]  30,720,000   (lc z=[NL,32] fits)
//  sgp  @ 79,360,000   [NE,32]    7,680,000   (ac sgp=[NN,128] fits)
//  dgp  @ 87,040,000   [NE,32]    7,680,000
//  smp  @ 94,720,000   [NE,128]  30,720,000   (ac smp=[NN,128] fits)
//  agg  @125,440,000   [NE,128]  30,720,000   (ac agg=[NN,128] fits)
//  stats@156,160,000   [1024]
//  pooled@156,161,024  [NB*128+NB]
//  msgs @156,180,000   [NL,128]  61,440,000   (ac msgs=[NE,128] fits)
//  iws  @217,620,000   int region (see below) ~1.25M
// total ~218,870,000 floats ~= 875 MB BSS
// ---------------------------------------------------------------------------
#define WS_TOTAL 218870000ull
__device__ __align__(16) float g_ws[WS_TOTAL];

__device__ __forceinline__ float dsigm(float x){ return 1.0f/(1.0f+__expf(-x)); }
__device__ __forceinline__ float dsilu(float x){ return x/(1.0f+__expf(-x)); }

struct f8 { float v[8]; };
__device__ __forceinline__ f8 load8(const float* __restrict__ p){
    f8 r;
    float4 a = *(const float4*)p;
    float4 b = *(const float4*)(p+4);
    r.v[0]=a.x; r.v[1]=a.y; r.v[2]=a.z; r.v[3]=a.w;
    r.v[4]=b.x; r.v[5]=b.y; r.v[6]=b.z; r.v[7]=b.w;
    return r;
}

// ======================== CSR build (once per launch) =======================
__global__ __launch_bounds__(256) void hist_kernel(const int* __restrict__ idx,
    int* __restrict__ cnt, int E)
{
    for (int i = blockIdx.x*256+threadIdx.x; i < E; i += gridDim.x*256)
        atomicAdd(&cnt[idx[i]], 1);
}

// block-level exclusive scan: 1024 elems/block (256 thr x 4)
__global__ __launch_bounds__(256) void scan1_kernel(const int* __restrict__ in,
    int* __restrict__ out, int* __restrict__ partials, int N)
{
    __shared__ int lds[256];
    const int t = threadIdx.x;
    const int base = blockIdx.x*1024 + t*4;
    int v0 = (base+0<N)? in[base+0]:0;
    int v1 = (base+1<N)? in[base+1]:0;
    int v2 = (base+2<N)? in[base+2]:0;
    int v3 = (base+3<N)? in[base+3]:0;
    int s = v0+v1+v2+v3;
    lds[t] = s;
    __syncthreads();
    for (int off=1; off<256; off<<=1){
        int tmp = (t>=off)? lds[t-off] : 0;
        __syncthreads();
        lds[t] += tmp;
        __syncthreads();
    }
    int excl = lds[t] - s;
    if (t==255) partials[blockIdx.x] = lds[255];
    if (base+0<N) out[base+0] = excl;
    if (base+1<N) out[base+1] = excl+v0;
    if (base+2<N) out[base+2] = excl+v0+v1;
    if (base+3<N) out[base+3] = excl+v0+v1+v2;
}

__global__ __launch_bounds__(256) void scan2_kernel(int* __restrict__ partials, int nblk)
{
    __shared__ int lds[256];
    const int t = threadIdx.x;
    int v = (t<nblk)? partials[t] : 0;
    lds[t] = v;
    __syncthreads();
    for (int off=1; off<256; off<<=1){
        int tmp = (t>=off)? lds[t-off] : 0;
        __syncthreads();
        lds[t] += tmp;
        __syncthreads();
    }
    if (t<nblk) partials[t] = lds[t] - v;   // exclusive
}

__global__ __launch_bounds__(256) void scan3_kernel(int* __restrict__ out,
    const int* __restrict__ partials, int N, int E)
{
    int i = blockIdx.x*256+threadIdx.x;
    if (i < N) out[i] += partials[i>>10];
    if (i == 0) out[N] = E;
}

__global__ __launch_bounds__(256) void copy_i_kernel(const int* __restrict__ src,
    int* __restrict__ dst, int N)
{
    for (int i = blockIdx.x*256+threadIdx.x; i < N; i += gridDim.x*256)
        dst[i] = src[i];
}

// slot assignment: pos[i] = unique slot among edges sharing idx[i]
__global__ __launch_bounds__(256) void pos_kernel(const int* __restrict__ idx,
    int* __restrict__ offs, int* __restrict__ pos, int E)
{
    for (int i = blockIdx.x*256+threadIdx.x; i < E; i += gridDim.x*256)
        pos[i] = atomicAdd(&offs[idx[i]], 1);
}

// ============================ dense GEMMs ==================================
template<int K, int C>
__global__ __launch_bounds__(256) void gemm_f4_kernel(const float* __restrict__ in,
    const float* __restrict__ W, const float* __restrict__ bias,
    float* __restrict__ out, int R)
{
    constexpr int CG = C/8;
    constexpr int RG = 256/CG;
    constexpr int ROWS = RG*4;
    __shared__ float wt[C*K];
    for (int i = threadIdx.x; i < K*C; i += 256){
        int k = i / C, c = i % C;
        wt[c*K + ((((k>>2) ^ ((c>>3)&7))<<2)) + (k&3)] = W[i];
    }
    __syncthreads();
    const int cg = threadIdx.x % CG;
    const int rg = threadIdx.x / CG;
    const int c0 = cg*8;
    const int r0 = blockIdx.x*ROWS + rg*4;
    float acc[4][8];
    #pragma unroll
    for (int i=0;i<4;++i){
        #pragma unroll
        for (int u=0;u<8;++u) acc[i][u]=0.f;
    }
    #pragma unroll 2
    for (int k4=0;k4<K/4;++k4){
        float4 av[4];
        #pragma unroll
        for (int i=0;i<4;++i){
            int r=r0+i;
            av[i] = (r<R) ? *(const float4*)(in + (size_t)r*K + k4*4) : make_float4(0.f,0.f,0.f,0.f);
        }
        #pragma unroll
        for (int u=0;u<8;++u){
            int c=c0+u;
            float4 wv = *(const float4*)(wt + c*K + ((k4 ^ ((c>>3)&7))<<2));
            #pragma unroll
            for (int i=0;i<4;++i)
                acc[i][u] = fmaf(av[i].w, wv.w, fmaf(av[i].z, wv.z, fmaf(av[i].y, wv.y, fmaf(av[i].x, wv.x, acc[i][u]))));
        }
    }
    float b[8];
    #pragma unroll
    for (int u=0;u<8;++u) b[u]=bias[c0+u];
    #pragma unroll
    for (int i=0;i<4;++i){
        int r=r0+i;
        if (r<R){
            float4 o0 = make_float4(acc[i][0]+b[0], acc[i][1]+b[1], acc[i][2]+b[2], acc[i][3]+b[3]);
            float4 o1 = make_float4(acc[i][4]+b[4], acc[i][5]+b[5], acc[i][6]+b[6], acc[i][7]+b[7]);
            *(float4*)(out + (size_t)r*C + c0)     = o0;
            *(float4*)(out + (size_t)r*C + c0 + 4) = o1;
        }
    }
}

template<int K, int C>
__global__ __launch_bounds__(256) void gemm_sc_kernel(const float* __restrict__ in,
    const float* __restrict__ W, const float* __restrict__ bias,
    float* __restrict__ out, int R)
{
    __shared__ float wl[K*C];
    for (int i=threadIdx.x;i<K*C;i+=256) wl[i]=W[i];
    __syncthreads();
    const int c  = threadIdx.x & (C-1);
    const int rl = threadIdx.x / C;
    constexpr int RPB = 256/C;
    float bv = bias[c];
    for (int r = blockIdx.x*RPB + rl; r < R; r += gridDim.x*RPB){
        const float* irow = in + (size_t)r*K;
        float acc = bv;
        #pragma unroll 4
        for (int k=0;k<K;++k) acc = fmaf(irow[k], wl[k*C+c], acc);
        out[(size_t)r*C + c] = acc;
    }
}

__global__ __launch_bounds__(256) void embed_a_kernel(const float* __restrict__ la,
    const float* __restrict__ w, const float* __restrict__ b, float* __restrict__ a)
{
    __shared__ float sw[32], sb[32];
    if (threadIdx.x < 32){ sw[threadIdx.x]=w[threadIdx.x]; sb[threadIdx.x]=b[threadIdx.x]; }
    __syncthreads();
    const int total = NL*8;
    for (int i = blockIdx.x*256+threadIdx.x; i < total; i += gridDim.x*256){
        int l = i >> 3, c0 = (i&7)*4;
        float lv = la[l];
        float4 o = make_float4(fmaf(lv,sw[c0],sb[c0]),   fmaf(lv,sw[c0+1],sb[c0+1]),
                               fmaf(lv,sw[c0+2],sb[c0+2]), fmaf(lv,sw[c0+3],sb[c0+3]));
        *(float4*)(a + (size_t)i*4) = o;
    }
}

// ============================ edge phase 1 =================================
template<int ED>
__global__ __launch_bounds__(256) void egc_gate_kernel(
    const float* __restrict__ ea,
    const float* __restrict__ sgp, const float* __restrict__ dgp,
    const int* __restrict__ row_idx, const int* __restrict__ col_idx,
    const float* __restrict__ eg_w, const float* __restrict__ eg_b,
    float* __restrict__ z, float* __restrict__ stat_sum, float* __restrict__ stat_sq,
    int R)
{
    constexpr int K = ED, C = ED;
    constexpr int CG = C/8;
    constexpr int RG = 256/CG;
    constexpr int ROWS = RG*4;
    __shared__ float wt[C*K];
    for (int i = threadIdx.x; i < K*C; i += 256){
        int k = i / C, c = i % C;
        wt[c*K + ((((k>>2) ^ ((c>>3)&7))<<2)) + (k&3)] = eg_w[i];
    }
    __syncthreads();
    const int cg = threadIdx.x % CG;
    const int rg = threadIdx.x / CG;
    const int c0 = cg*8;
    const int r0 = blockIdx.x*ROWS + rg*4;
    float acc[4][8];
    #pragma unroll
    for (int i=0;i<4;++i){
        #pragma unroll
        for (int u=0;u<8;++u) acc[i][u]=0.f;
    }
    #pragma unroll 2
    for (int k4=0;k4<K/4;++k4){
        float4 av[4];
        #pragma unroll
        for (int i=0;i<4;++i){
            int r=r0+i;
            av[i] = (r<R) ? *(const float4*)(ea + (size_t)r*K + k4*4) : make_float4(0.f,0.f,0.f,0.f);
        }
        #pragma unroll
        for (int u=0;u<8;++u){
            int c=c0+u;
            float4 wv = *(const float4*)(wt + c*K + ((k4 ^ ((c>>3)&7))<<2));
            #pragma unroll
            for (int i=0;i<4;++i)
                acc[i][u] = fmaf(av[i].w, wv.w, fmaf(av[i].z, wv.z, fmaf(av[i].y, wv.y, fmaf(av[i].x, wv.x, acc[i][u]))));
        }
    }
    float eb[8];
    #pragma unroll
    for (int u=0;u<8;++u) eb[u] = eg_b[c0+u];
    float lsum[8], lsq[8];
    #pragma unroll
    for (int u=0;u<8;++u){ lsum[u]=0.f; lsq[u]=0.f; }
    #pragma unroll
    for (int i=0;i<4;++i){
        int r = r0+i;
        if (r < R){
            int rj = row_idx[r], cj = col_idx[r];
            f8 sg = load8(sgp + (size_t)rj*C + c0);
            f8 dg = load8(dgp + (size_t)cj*C + c0);
            f8 ev = load8(ea  + (size_t)r*C + c0);
            float zr[8];
            #pragma unroll
            for (int u=0;u<8;++u){
                float gate = dsigm(acc[i][u] + sg.v[u] + dg.v[u] + eb[u]);
                float t = gate * ev.v[u];
                float zs = dsilu(t);
                zr[u] = zs;
                lsum[u] += zs; lsq[u] += zs*zs;
            }
            *(float4*)(z + (size_t)r*C + c0)   = make_float4(zr[0],zr[1],zr[2],zr[3]);
            *(float4*)(z + (size_t)r*C + c0+4) = make_float4(zr[4],zr[5],zr[6],zr[7]);
        }
    }
    __syncthreads();                 // all wt reads complete -> reuse as stats
    float* ssum = wt;
    float* ssq  = wt + C;
    if (threadIdx.x < 2*C) wt[threadIdx.x] = 0.f;
    __syncthreads();
    #pragma unroll
    for (int u=0;u<8;++u){ atomicAdd(&ssum[c0+u], lsum[u]); atomicAdd(&ssq[c0+u], lsq[u]); }
    __syncthreads();
    if (threadIdx.x < C){
        atomicAdd(&stat_sum[threadIdx.x], ssum[threadIdx.x]);
        atomicAdd(&stat_sq[threadIdx.x],  ssq[threadIdx.x]);
    }
}

__global__ void bn_finalize_kernel(const float* __restrict__ sum, const float* __restrict__ sq,
    const float* __restrict__ gamma, const float* __restrict__ beta,
    float* __restrict__ A, float* __restrict__ B, float inv_n, int C)
{
    int c = threadIdx.x;
    if (c < C){
        float mu  = sum[c]*inv_n;
        float var = sq[c]*inv_n - mu*mu;
        float rs  = rsqrtf(var + 1e-5f);
        float a   = gamma[c]*rs;
        A[c] = a;
        B[c] = fmaf(-mu, a, beta[c]);
    }
}

// ============================ edge phase 2 =================================
// ea_new = z*A+B; ea += ea_new (residual); msg = smp[row] + ea_new@em_w + em_b
// -> plain store to msgs[pos[r]] (CSR slot), NO atomics.
template<int ED, int ND>
__global__ __launch_bounds__(256) void egc_msg_kernel(
    const float* __restrict__ z, float* __restrict__ ea,
    const float* __restrict__ bnA, const float* __restrict__ bnB,
    const float* __restrict__ smp,
    const int* __restrict__ row_idx, const int* __restrict__ pos,
    const float* __restrict__ em_w, const float* __restrict__ em_b,
    float* __restrict__ msgs, int R)
{
    constexpr int K = ED, C = ND;
    constexpr int CG = C/8;
    constexpr int RG = 256/CG;
    constexpr int ROWS = RG*4;
    __shared__ float wt[C*K];
    for (int i=threadIdx.x;i<K*C;i+=256){
        int k=i/C, c=i%C;
        wt[c*K + ((((k>>2) ^ ((c>>3)&7))<<2)) + (k&3)] = em_w[i];
    }
    __syncthreads();
    const int cg = threadIdx.x % CG;
    const int rg = threadIdx.x / CG;
    const int c0 = cg*8;
    const int r0 = blockIdx.x*ROWS + rg*4;
    float acc[4][8];
    #pragma unroll
    for (int i=0;i<4;++i){
        #pragma unroll
        for (int u=0;u<8;++u) acc[i][u]=0.f;
    }
    #pragma unroll 2
    for (int k4=0;k4<K/4;++k4){
        const float4 Af = *(const float4*)(bnA + k4*4);
        const float4 Bf = *(const float4*)(bnB + k4*4);
        float4 av[4];
        #pragma unroll
        for (int i=0;i<4;++i){
            int r=r0+i;
            if (r<R){
                float4 zv = *(const float4*)(z + (size_t)r*K + k4*4);
                float4 t;
                t.x = fmaf(zv.x, Af.x, Bf.x);
                t.y = fmaf(zv.y, Af.y, Bf.y);
                t.z = fmaf(zv.z, Af.z, Bf.z);
                t.w = fmaf(zv.w, Af.w, Bf.w);
                av[i]=t;
                if (cg==0){   // residual: ea += ea_new (one writer per row)
                    float4 evv = *(const float4*)(ea + (size_t)r*K + k4*4);
                    evv.x+=t.x; evv.y+=t.y; evv.z+=t.z; evv.w+=t.w;
                    *(float4*)(ea + (size_t)r*K + k4*4) = evv;
                }
            } else av[i]=make_float4(0.f,0.f,0.f,0.f);
        }
        #pragma unroll
        for (int u=0;u<8;++u){
            int c=c0+u;
            float4 wv = *(const float4*)(wt + c*K + ((k4 ^ ((c>>3)&7))<<2));
            #pragma unroll
            for (int i=0;i<4;++i)
                acc[i][u] = fmaf(av[i].w, wv.w, fmaf(av[i].z, wv.z, fmaf(av[i].y, wv.y, fmaf(av[i].x, wv.x, acc[i][u]))));
        }
    }
    float mb[8];
    #pragma unroll
    for (int u=0;u<8;++u) mb[u]=em_b[c0+u];
    #pragma unroll
    for (int i=0;i<4;++i){
        int r=r0+i;
        if (r<R){
            int rj=row_idx[r];
            int p = pos[r];
            f8 sm = load8(smp + (size_t)rj*C + c0);
            float4 o0 = make_float4(acc[i][0]+mb[0]+sm.v[0], acc[i][1]+mb[1]+sm.v[1],
                                    acc[i][2]+mb[2]+sm.v[2], acc[i][3]+mb[3]+sm.v[3]);
            float4 o1 = make_float4(acc[i][4]+mb[4]+sm.v[4], acc[i][5]+mb[5]+sm.v[5],
                                    acc[i][6]+mb[6]+sm.v[6], acc[i][7]+mb[7]+sm.v[7]);
            *(float4*)(msgs + (size_t)p*C + c0)     = o0;
            *(float4*)(msgs + (size_t)p*C + c0 + 4) = o1;
        }
    }
}

// ================ CSR gather: agg[n] = sum of msg rows; + silu stats =======
__global__ __launch_bounds__(256) void gather_stats_kernel(
    const float* __restrict__ msgs, const int* __restrict__ rowptr,
    float* __restrict__ agg, float* __restrict__ stat_sum, float* __restrict__ stat_sq,
    int N)
{
    __shared__ float ssum[128], ssq[128];
    if (threadIdx.x < 128){ ssum[threadIdx.x]=0.f; ssq[threadIdx.x]=0.f; }
    __syncthreads();
    const int lane = threadIdx.x & 31, grp = threadIdx.x >> 5;
    const int c0 = lane*4;
    float ls[4]={0.f,0.f,0.f,0.f}, lq[4]={0.f,0.f,0.f,0.f};
    for (int n = blockIdx.x*8 + grp; n < N; n += gridDim.x*8){
        int s = rowptr[n], e = rowptr[n+1];
        float a0=0.f,a1=0.f,a2=0.f,a3=0.f;
        for (int i=s;i<e;++i){
            float4 v = *(const float4*)(msgs + (size_t)i*128 + c0);
            a0+=v.x; a1+=v.y; a2+=v.z; a3+=v.w;
        }
        *(float4*)(agg + (size_t)n*128 + c0) = make_float4(a0,a1,a2,a3);
        float t;
        t=dsilu(a0); ls[0]+=t; lq[0]+=t*t;
        t=dsilu(a1); ls[1]+=t; lq[1]+=t*t;
        t=dsilu(a2); ls[2]+=t; lq[2]+=t*t;
        t=dsilu(a3); ls[3]+=t; lq[3]+=t*t;
    }
    #pragma unroll
    for (int j=0;j<4;++j){ atomicAdd(&ssum[c0+j], ls[j]); atomicAdd(&ssq[c0+j], lq[j]); }
    __syncthreads();
    if (threadIdx.x < 128){
        atomicAdd(&stat_sum[threadIdx.x], ssum[threadIdx.x]);
        atomicAdd(&stat_sq[threadIdx.x],  ssq[threadIdx.x]);
    }
}

// x += silu(agg)*A + B
__global__ __launch_bounds__(256) void node_apply_kernel(float* __restrict__ x,
    const float* __restrict__ agg,
    const float* __restrict__ A, const float* __restrict__ B, int total4)
{
    __shared__ float sA[128], sB[128];
    if (threadIdx.x<128){ sA[threadIdx.x]=A[threadIdx.x]; sB[threadIdx.x]=B[threadIdx.x]; }
    __syncthreads();
    for (int i = blockIdx.x*256+threadIdx.x; i < total4; i += gridDim.x*256){
        int c0 = (i*4) & 127;
        float4 v  = *(const float4*)(agg + (size_t)i*4);
        float4 xv = *(const float4*)(x   + (size_t)i*4);
        xv.x += fmaf(dsilu(v.x), sA[c0],   sB[c0]);
        xv.y += fmaf(dsilu(v.y), sA[c0+1], sB[c0+1]);
        xv.z += fmaf(dsilu(v.z), sA[c0+2], sB[c0+2]);
        xv.w += fmaf(dsilu(v.w), sA[c0+3], sB[c0+3]);
        *(float4*)(x + (size_t)i*4) = xv;
    }
}

__global__ __launch_bounds__(256) void pool_kernel(const float* __restrict__ h,
    const int* __restrict__ batch, float* __restrict__ pooled, float* __restrict__ cnt)
{
    const int total = NN*32;
    for (int i = blockIdx.x*256+threadIdx.x; i < total; i += gridDim.x*256){
        int n = i >> 5, c0 = (i&31)*4;
        int b = batch[n];
        float4 v = *(const float4*)(h + (size_t)n*128 + c0);
        atomicAdd(&pooled[b*128+c0],   v.x);
        atomicAdd(&pooled[b*128+c0+1], v.y);
        atomicAdd(&pooled[b*128+c0+2], v.z);
        atomicAdd(&pooled[b*128+c0+3], v.w);
        if (c0==0) atomicAdd(&cnt[b], 1.f);
    }
}

__global__ __launch_bounds__(128) void mlp_kernel(const float* __restrict__ pooled,
    const float* __restrict__ cnt,
    const float* __restrict__ W1, const float* __restrict__ b1,
    const float* __restrict__ W2, const float* __restrict__ b2,
    const float* __restrict__ W3, const float* __restrict__ b3,
    float* __restrict__ out)
{
    __shared__ float p[128], o1[128], red[64];
    int g = blockIdx.x, t = threadIdx.x;
    float c = fmaxf(cnt[g], 1.0f);
    p[t] = pooled[g*128+t] / c;
    __syncthreads();
    float acc = b1[t];
    for (int k=0;k<128;++k) acc = fmaf(p[k], W1[k*128+t], acc);
    o1[t] = dsilu(acc);
    __syncthreads();
    if (t < 64){
        float a2 = b2[t];
        for (int k=0;k<128;++k) a2 = fmaf(o1[k], W2[k*64+t], a2);
        red[t] = dsilu(a2) * W3[t];
    }
    __syncthreads();
    for (int s2=32; s2>0; s2>>=1){
        if (t < s2) red[t] += red[t+s2];
        __syncthreads();
    }
    if (t==0) out[g] = red[0] + b3[0];
}

// ---------------------------------------------------------------------------
extern "C" void kernel_launch(void* const* d_in, const int* in_sizes, int n_in,
                              void* d_out, int out_size, void* d_ws, size_t ws_size,
                              hipStream_t stream)
{
    (void)in_sizes; (void)n_in; (void)out_size; (void)d_ws; (void)ws_size;

    const float* x_in      = (const float*)d_in[0];
    const int*   edge_index= (const int*)d_in[1];
    const float* edge_attr = (const float*)d_in[2];
    const int*   line_index= (const int*)d_in[3];
    const float* line_attr = (const float*)d_in[4];
    const int*   batch     = (const int*)d_in[5];
    const float* W_ae=(const float*)d_in[6];  const float* b_ae=(const float*)d_in[7];
    const float* W_ee=(const float*)d_in[8];  const float* b_ee=(const float*)d_in[9];
    const float* W_ng=(const float*)d_in[10]; const float* b_ng=(const float*)d_in[11];
    const float* W1=(const float*)d_in[12];   const float* b1=(const float*)d_in[13];
    const float* W2=(const float*)d_in[14];   const float* b2=(const float*)d_in[15];
    const float* W3=(const float*)d_in[16];   const float* b3=(const float*)d_in[17];
    const float* P[28];
    for (int i=0;i<28;++i) P[i] = (const float*)d_in[18+i];
    const float* const* LCQ = P;        // lc_* in _P order
    const float* const* ACQ = P + 14;   // ac_*

    float* ws = nullptr;
    hipGetSymbolAddress((void**)&ws, HIP_SYMBOL(g_ws));
    float* h     = ws;                        // [NN,128]
    float* e     = ws + 2560000;              // [NE,128]
    float* a     = ws + 33280000;             // [NL,32]
    float* z     = ws + 48640000;             // [NE,128] (>= NL*32)
    float* sgp   = ws + 79360000;             // [NE,32]  (>= NN*128)
    float* dgp   = ws + 87040000;             // [NE,32]
    float* smp   = ws + 94720000;             // [NE,128] (>= NN*128)
    float* agg   = ws + 125440000;            // [NE,128] (>= NN*128)
    float* stats = ws + 156160000;            // 1024
    float* pooled= stats + 1024;              // [NB,128]+NB
    float* cnt   = pooled + NB*128;
    float* msgs  = ws + 156180000;            // [NL,128] (>= NE*128)
    int*   iws   = (int*)(ws + 217620000);
    int* rowptr_ac = iws;                     // NN+1
    int* offs_ac   = iws + 20001;             // NN (doubles as cnt)
    int* rowptr_lc = iws + 40001;             // NE+1
    int* offs_lc   = iws + 280002;            // NE (doubles as cnt)
    int* pos_ac    = iws + 520002;            // NE
    int* pos_lc    = iws + 760002;            // NL
    int* partials  = iws + 1240002;           // <=1024

    const int* row  = edge_index;
    const int* col  = edge_index + NE;
    const int* lrow = line_index;
    const int* lcol = line_index + NL;

    // ---- CSR build (both graphs), once per launch
    auto build_csr = [&](const int* idx, int N, int E, int* rowptr, int* offs, int* pos){
        hipMemsetAsync(offs, 0, (size_t)N*sizeof(int), stream);
        hist_kernel<<<256,256,0,stream>>>(idx, offs, E);
        int nblk = cdiv(N,1024);
        scan1_kernel<<<nblk,256,0,stream>>>(offs, rowptr, partials, N);
        scan2_kernel<<<1,256,0,stream>>>(partials, nblk);
        scan3_kernel<<<cdiv(N,256),256,0,stream>>>(rowptr, partials, N, E);
        copy_i_kernel<<<256,256,0,stream>>>(rowptr, offs, N);
        pos_kernel<<<256,256,0,stream>>>(idx, offs, pos, E);
    };
    build_csr(col,  NN, NE, rowptr_ac, offs_ac, pos_ac);
    build_csr(lcol, NE, NL, rowptr_lc, offs_lc, pos_lc);

    // ---- embeddings
    gemm_sc_kernel<92,128><<<4096,256,0,stream>>>(x_in,      W_ae, b_ae, h, NN);
    gemm_sc_kernel<41,128><<<8192,256,0,stream>>>(edge_attr, W_ee, b_ee, e, NE);
    embed_a_kernel<<<2048,256,0,stream>>>(line_attr, W_ng, b_ng, a);

    auto run_egc = [&](float* xb, int Rx, float* eab, int Re, bool big,
                       const int* ridx, const int* cidx,
                       const int* rowptr, const int* pos,
                       const float* const* q, int li){
        const float* sg_w = q[0]  + (size_t)li*(big?16384:4096);
        const float* sg_b = q[1]  + li*(big?128:32);
        const float* dg_w = q[2]  + (size_t)li*(big?16384:4096);
        const float* dg_b = q[3]  + li*(big?128:32);
        const float* eg_w = q[4]  + (size_t)li*(big?16384:1024);
        const float* eg_b = q[5]  + li*(big?128:32);
        const float* bne_g= q[6]  + li*(big?128:32);
        const float* bne_b= q[7]  + li*(big?128:32);
        const float* sm_w = q[8]  + (size_t)li*16384;
        const float* sm_b = q[9]  + li*128;
        const float* em_w = q[10] + (size_t)li*(big?16384:4096);
        const float* em_b = q[11] + li*128;
        const float* bnn_g= q[12] + li*128;
        const float* bnn_b= q[13] + li*128;

        // node projections
        if (big){
            gemm_f4_kernel<128,128><<<cdiv(Rx,64),256,0,stream>>>(xb, sg_w, sg_b, sgp, Rx);
            gemm_f4_kernel<128,128><<<cdiv(Rx,64),256,0,stream>>>(xb, dg_w, dg_b, dgp, Rx);
        } else {
            gemm_f4_kernel<128,32><<<cdiv(Rx,256),256,0,stream>>>(xb, sg_w, sg_b, sgp, Rx);
            gemm_f4_kernel<128,32><<<cdiv(Rx,256),256,0,stream>>>(xb, dg_w, dg_b, dgp, Rx);
        }
        gemm_f4_kernel<128,128><<<cdiv(Rx,64),256,0,stream>>>(xb, sm_w, sm_b, smp, Rx);

        hipMemsetAsync(stats, 0, 1024*sizeof(float), stream);
        if (big)
            egc_gate_kernel<128><<<cdiv(Re,64),256,0,stream>>>(eab, sgp, dgp, ridx, cidx,
                eg_w, eg_b, z, stats, stats+128, Re);
        else
            egc_gate_kernel<32><<<cdiv(Re,256),256,0,stream>>>(eab, sgp, dgp, ridx, cidx,
                eg_w, eg_b, z, stats, stats+128, Re);
        bn_finalize_kernel<<<1,128,0,stream>>>(stats, stats+128, bne_g, bne_b,
            stats+256, stats+384, 1.0f/(float)Re, big?128:32);

        // message phase: sorted stores, no atomics
        if (big)
            egc_msg_kernel<128,128><<<cdiv(Re,64),256,0,stream>>>(z, eab, stats+256, stats+384,
                smp, ridx, pos, em_w, em_b, msgs, Re);
        else
            egc_msg_kernel<32,128><<<cdiv(Re,64),256,0,stream>>>(z, eab, stats+256, stats+384,
                smp, ridx, pos, em_w, em_b, msgs, Re);

        // CSR gather + fused node stats
        gather_stats_kernel<<<2048,256,0,stream>>>(msgs, rowptr, agg,
            stats+512, stats+640, Rx);
        bn_finalize_kernel<<<1,128,0,stream>>>(stats+512, stats+640, bnn_g, bnn_b,
            stats+768, stats+896, 1.0f/(float)Rx, 128);
        node_apply_kernel<<<2048,256,0,stream>>>(xb, agg, stats+768, stats+896, Rx*32);
    };

    for (int i=0;i<3;++i){
        run_egc(e, NE, a, NL, false, lrow, lcol, rowptr_lc, pos_lc, LCQ, i);  // line-graph
        run_egc(h, NN, e, NE, true,  row,  col,  rowptr_ac, pos_ac, ACQ, i);  // atom-graph
    }
    for (int i=3;i<6;++i)
        run_egc(h, NN, e, NE, true, row, col, rowptr_ac, pos_ac, ACQ, i);     // GCN layers

    // ---- pooling + MLP head
    hipMemsetAsync(pooled, 0, ((size_t)NB*128 + NB)*sizeof(float), stream);
    pool_kernel<<<1024,256,0,stream>>>(h, batch, pooled, cnt);
    mlp_kernel<<<NB,128,0,stream>>>(pooled, cnt, W1,b1,W2,b2,W3,b3, (float*)d_out);
}

// Round 11
// 10777.803 us; speedup vs baseline: 1.7821x; 1.0431x over previous
//
#include <hip/hip_runtime.h>
#include <math.h>

#define NN 20000
#define NE 240000
#define NL 480000
#define NB 128

static inline int cdiv(int a, int b){ return (a+b-1)/b; }

// ---------------------------------------------------------------------------
// Workspace in device-global BSS (d_ws unused; BSS is load-time alloc,
// graph-capture safe). Every sub-buffer fully (re)initialized per call.
// Layout identical to round 9 (see offsets below). ~875 MB BSS.
// ---------------------------------------------------------------------------
#define WS_TOTAL 218870000ull
__device__ __align__(16) float g_ws[WS_TOTAL];

__device__ __forceinline__ float dsigm(float x){ return 1.0f/(1.0f+__expf(-x)); }
__device__ __forceinline__ float dsilu(float x){ return x/(1.0f+__expf(-x)); }

struct f8 { float v[8]; };
__device__ __forceinline__ f8 load8(const float* __restrict__ p){
    f8 r;
    float4 a = *(const float4*)p;
    float4 b = *(const float4*)(p+4);
    r.v[0]=a.x; r.v[1]=a.y; r.v[2]=a.z; r.v[3]=a.w;
    r.v[4]=b.x; r.v[5]=b.y; r.v[6]=b.z; r.v[7]=b.w;
    return r;
}

// ======================== CSR build (once per launch) =======================
__global__ __launch_bounds__(256) void hist_kernel(const int* __restrict__ idx,
    int* __restrict__ cnt, int E)
{
    for (int i = blockIdx.x*256+threadIdx.x; i < E; i += gridDim.x*256)
        atomicAdd(&cnt[idx[i]], 1);
}

__global__ __launch_bounds__(256) void scan1_kernel(const int* __restrict__ in,
    int* __restrict__ out, int* __restrict__ partials, int N)
{
    __shared__ int lds[256];
    const int t = threadIdx.x;
    const int base = blockIdx.x*1024 + t*4;
    int v0 = (base+0<N)? in[base+0]:0;
    int v1 = (base+1<N)? in[base+1]:0;
    int v2 = (base+2<N)? in[base+2]:0;
    int v3 = (base+3<N)? in[base+3]:0;
    int s = v0+v1+v2+v3;
    lds[t] = s;
    __syncthreads();
    for (int off=1; off<256; off<<=1){
        int tmp = (t>=off)? lds[t-off] : 0;
        __syncthreads();
        lds[t] += tmp;
        __syncthreads();
    }
    int excl = lds[t] - s;
    if (t==255) partials[blockIdx.x] = lds[255];
    if (base+0<N) out[base+0] = excl;
    if (base+1<N) out[base+1] = excl+v0;
    if (base+2<N) out[base+2] = excl+v0+v1;
    if (base+3<N) out[base+3] = excl+v0+v1+v2;
}

__global__ __launch_bounds__(256) void scan2_kernel(int* __restrict__ partials, int nblk)
{
    __shared__ int lds[256];
    const int t = threadIdx.x;
    int v = (t<nblk)? partials[t] : 0;
    lds[t] = v;
    __syncthreads();
    for (int off=1; off<256; off<<=1){
        int tmp = (t>=off)? lds[t-off] : 0;
        __syncthreads();
        lds[t] += tmp;
        __syncthreads();
    }
    if (t<nblk) partials[t] = lds[t] - v;   // exclusive
}

__global__ __launch_bounds__(256) void scan3_kernel(int* __restrict__ out,
    const int* __restrict__ partials, int N, int E)
{
    int i = blockIdx.x*256+threadIdx.x;
    if (i < N) out[i] += partials[i>>10];
    if (i == 0) out[N] = E;
}

__global__ __launch_bounds__(256) void copy_i_kernel(const int* __restrict__ src,
    int* __restrict__ dst, int N)
{
    for (int i = blockIdx.x*256+threadIdx.x; i < N; i += gridDim.x*256)
        dst[i] = src[i];
}

__global__ __launch_bounds__(256) void pos_kernel(const int* __restrict__ idx,
    int* __restrict__ offs, int* __restrict__ pos, int E)
{
    for (int i = blockIdx.x*256+threadIdx.x; i < E; i += gridDim.x*256)
        pos[i] = atomicAdd(&offs[idx[i]], 1);
}

// ============================ dense GEMMs ==================================
// No-LDS variant: weights read directly from global [k][c] (64KB, L2-resident,
// shared by all blocks). Removes the 64KB LDS tile that capped occupancy at
// 2 blocks/CU (21% measured, round 9).
template<int K, int C>
__global__ __launch_bounds__(256) void gemm_f4_kernel(const float* __restrict__ in,
    const float* __restrict__ W, const float* __restrict__ bias,
    float* __restrict__ out, int R)
{
    constexpr int CG = C/8;
    constexpr int RG = 256/CG;
    constexpr int ROWS = RG*4;
    const int cg = threadIdx.x % CG;
    const int rg = threadIdx.x / CG;
    const int c0 = cg*8;
    const int r0 = blockIdx.x*ROWS + rg*4;
    float acc[4][8];
    #pragma unroll
    for (int i=0;i<4;++i){
        #pragma unroll
        for (int u=0;u<8;++u) acc[i][u]=0.f;
    }
    for (int k4=0;k4<K/4;++k4){
        float4 av[4];
        #pragma unroll
        for (int i=0;i<4;++i){
            int r=r0+i;
            av[i] = (r<R) ? *(const float4*)(in + (size_t)r*K + k4*4) : make_float4(0.f,0.f,0.f,0.f);
        }
        const float* wp = W + (size_t)k4*4*C + c0;
        #pragma unroll
        for (int kk=0;kk<4;++kk){
            float4 wa = *(const float4*)(wp + kk*C);
            float4 wb = *(const float4*)(wp + kk*C + 4);
            #pragma unroll
            for (int i=0;i<4;++i){
                float aval = (kk==0)?av[i].x:(kk==1)?av[i].y:(kk==2)?av[i].z:av[i].w;
                acc[i][0]=fmaf(aval,wa.x,acc[i][0]);
                acc[i][1]=fmaf(aval,wa.y,acc[i][1]);
                acc[i][2]=fmaf(aval,wa.z,acc[i][2]);
                acc[i][3]=fmaf(aval,wa.w,acc[i][3]);
                acc[i][4]=fmaf(aval,wb.x,acc[i][4]);
                acc[i][5]=fmaf(aval,wb.y,acc[i][5]);
                acc[i][6]=fmaf(aval,wb.z,acc[i][6]);
                acc[i][7]=fmaf(aval,wb.w,acc[i][7]);
            }
        }
    }
    float b[8];
    #pragma unroll
    for (int u=0;u<8;++u) b[u]=bias[c0+u];
    #pragma unroll
    for (int i=0;i<4;++i){
        int r=r0+i;
        if (r<R){
            float4 o0 = make_float4(acc[i][0]+b[0], acc[i][1]+b[1], acc[i][2]+b[2], acc[i][3]+b[3]);
            float4 o1 = make_float4(acc[i][4]+b[4], acc[i][5]+b[5], acc[i][6]+b[6], acc[i][7]+b[7]);
            *(float4*)(out + (size_t)r*C + c0)     = o0;
            *(float4*)(out + (size_t)r*C + c0 + 4) = o1;
        }
    }
}

template<int K, int C>
__global__ __launch_bounds__(256) void gemm_sc_kernel(const float* __restrict__ in,
    const float* __restrict__ W, const float* __restrict__ bias,
    float* __restrict__ out, int R)
{
    __shared__ float wl[K*C];
    for (int i=threadIdx.x;i<K*C;i+=256) wl[i]=W[i];
    __syncthreads();
    const int c  = threadIdx.x & (C-1);
    const int rl = threadIdx.x / C;
    constexpr int RPB = 256/C;
    float bv = bias[c];
    for (int r = blockIdx.x*RPB + rl; r < R; r += gridDim.x*RPB){
        const float* irow = in + (size_t)r*K;
        float acc = bv;
        #pragma unroll 4
        for (int k=0;k<K;++k) acc = fmaf(irow[k], wl[k*C+c], acc);
        out[(size_t)r*C + c] = acc;
    }
}

__global__ __launch_bounds__(256) void embed_a_kernel(const float* __restrict__ la,
    const float* __restrict__ w, const float* __restrict__ b, float* __restrict__ a)
{
    __shared__ float sw[32], sb[32];
    if (threadIdx.x < 32){ sw[threadIdx.x]=w[threadIdx.x]; sb[threadIdx.x]=b[threadIdx.x]; }
    __syncthreads();
    const int total = NL*8;
    for (int i = blockIdx.x*256+threadIdx.x; i < total; i += gridDim.x*256){
        int l = i >> 3, c0 = (i&7)*4;
        float lv = la[l];
        float4 o = make_float4(fmaf(lv,sw[c0],sb[c0]),   fmaf(lv,sw[c0+1],sb[c0+1]),
                               fmaf(lv,sw[c0+2],sb[c0+2]), fmaf(lv,sw[c0+3],sb[c0+3]));
        *(float4*)(a + (size_t)i*4) = o;
    }
}

// ============================ edge phase 1 =================================
// gate = sigmoid(sgp[row]+dgp[col]+ea@eg_w+eg_b); z = silu(gate*ea); stats.
// No-LDS weights; 1KB LDS stats scratch only.
template<int ED>
__global__ __launch_bounds__(256) void egc_gate_kernel(
    const float* __restrict__ ea,
    const float* __restrict__ sgp, const float* __restrict__ dgp,
    const int* __restrict__ row_idx, const int* __restrict__ col_idx,
    const float* __restrict__ eg_w, const float* __restrict__ eg_b,
    float* __restrict__ z, float* __restrict__ stat_sum, float* __restrict__ stat_sq,
    int R)
{
    constexpr int K = ED, C = ED;
    constexpr int CG = C/8;
    constexpr int RG = 256/CG;
    constexpr int ROWS = RG*4;
    __shared__ float sred[2*C];
    const int cg = threadIdx.x % CG;
    const int rg = threadIdx.x / CG;
    const int c0 = cg*8;
    const int r0 = blockIdx.x*ROWS + rg*4;
    float acc[4][8];
    #pragma unroll
    for (int i=0;i<4;++i){
        #pragma unroll
        for (int u=0;u<8;++u) acc[i][u]=0.f;
    }
    for (int k4=0;k4<K/4;++k4){
        float4 av[4];
        #pragma unroll
        for (int i=0;i<4;++i){
            int r=r0+i;
            av[i] = (r<R) ? *(const float4*)(ea + (size_t)r*K + k4*4) : make_float4(0.f,0.f,0.f,0.f);
        }
        const float* wp = eg_w + (size_t)k4*4*C + c0;
        #pragma unroll
        for (int kk=0;kk<4;++kk){
            float4 wa = *(const float4*)(wp + kk*C);
            float4 wb = *(const float4*)(wp + kk*C + 4);
            #pragma unroll
            for (int i=0;i<4;++i){
                float aval = (kk==0)?av[i].x:(kk==1)?av[i].y:(kk==2)?av[i].z:av[i].w;
                acc[i][0]=fmaf(aval,wa.x,acc[i][0]);
                acc[i][1]=fmaf(aval,wa.y,acc[i][1]);
                acc[i][2]=fmaf(aval,wa.z,acc[i][2]);
                acc[i][3]=fmaf(aval,wa.w,acc[i][3]);
                acc[i][4]=fmaf(aval,wb.x,acc[i][4]);
                acc[i][5]=fmaf(aval,wb.y,acc[i][5]);
                acc[i][6]=fmaf(aval,wb.z,acc[i][6]);
                acc[i][7]=fmaf(aval,wb.w,acc[i][7]);
            }
        }
    }
    float eb[8];
    #pragma unroll
    for (int u=0;u<8;++u) eb[u] = eg_b[c0+u];
    float lsum[8], lsq[8];
    #pragma unroll
    for (int u=0;u<8;++u){ lsum[u]=0.f; lsq[u]=0.f; }
    #pragma unroll
    for (int i=0;i<4;++i){
        int r = r0+i;
        if (r < R){
            int rj = row_idx[r], cj = col_idx[r];
            f8 sg = load8(sgp + (size_t)rj*C + c0);
            f8 dg = load8(dgp + (size_t)cj*C + c0);
            f8 ev = load8(ea  + (size_t)r*C + c0);
            float zr[8];
            #pragma unroll
            for (int u=0;u<8;++u){
                float gate = dsigm(acc[i][u] + sg.v[u] + dg.v[u] + eb[u]);
                float t = gate * ev.v[u];
                float zs = dsilu(t);
                zr[u] = zs;
                lsum[u] += zs; lsq[u] += zs*zs;
            }
            *(float4*)(z + (size_t)r*C + c0)   = make_float4(zr[0],zr[1],zr[2],zr[3]);
            *(float4*)(z + (size_t)r*C + c0+4) = make_float4(zr[4],zr[5],zr[6],zr[7]);
        }
    }
    if (threadIdx.x < 2*C) sred[threadIdx.x] = 0.f;
    __syncthreads();
    float* ssum = sred;
    float* ssq  = sred + C;
    #pragma unroll
    for (int u=0;u<8;++u){ atomicAdd(&ssum[c0+u], lsum[u]); atomicAdd(&ssq[c0+u], lsq[u]); }
    __syncthreads();
    if (threadIdx.x < C){
        atomicAdd(&stat_sum[threadIdx.x], ssum[threadIdx.x]);
        atomicAdd(&stat_sq[threadIdx.x],  ssq[threadIdx.x]);
    }
}

__global__ void bn_finalize_kernel(const float* __restrict__ sum, const float* __restrict__ sq,
    const float* __restrict__ gamma, const float* __restrict__ beta,
    float* __restrict__ A, float* __restrict__ B, float inv_n, int C)
{
    int c = threadIdx.x;
    if (c < C){
        float mu  = sum[c]*inv_n;
        float var = sq[c]*inv_n - mu*mu;
        float rs  = rsqrtf(var + 1e-5f);
        float a   = gamma[c]*rs;
        A[c] = a;
        B[c] = fmaf(-mu, a, beta[c]);
    }
}

// ============================ edge phase 2 =================================
// ea_new = z*A+B; ea += ea_new (residual); msg = smp[row] + ea_new@em_w + em_b
// -> plain store to msgs[pos[r]] (CSR slot). No-LDS weights.
template<int ED, int ND>
__global__ __launch_bounds__(256) void egc_msg_kernel(
    const float* __restrict__ z, float* __restrict__ ea,
    const float* __restrict__ bnA, const float* __restrict__ bnB,
    const float* __restrict__ smp,
    const int* __restrict__ row_idx, const int* __restrict__ pos,
    const float* __restrict__ em_w, const float* __restrict__ em_b,
    float* __restrict__ msgs, int R)
{
    constexpr int K = ED, C = ND;
    constexpr int CG = C/8;
    constexpr int RG = 256/CG;
    constexpr int ROWS = RG*4;
    const int cg = threadIdx.x % CG;
    const int rg = threadIdx.x / CG;
    const int c0 = cg*8;
    const int r0 = blockIdx.x*ROWS + rg*4;
    float acc[4][8];
    #pragma unroll
    for (int i=0;i<4;++i){
        #pragma unroll
        for (int u=0;u<8;++u) acc[i][u]=0.f;
    }
    for (int k4=0;k4<K/4;++k4){
        const float4 Af = *(const float4*)(bnA + k4*4);
        const float4 Bf = *(const float4*)(bnB + k4*4);
        float4 av[4];
        #pragma unroll
        for (int i=0;i<4;++i){
            int r=r0+i;
            if (r<R){
                float4 zv = *(const float4*)(z + (size_t)r*K + k4*4);
                float4 t;
                t.x = fmaf(zv.x, Af.x, Bf.x);
                t.y = fmaf(zv.y, Af.y, Bf.y);
                t.z = fmaf(zv.z, Af.z, Bf.z);
                t.w = fmaf(zv.w, Af.w, Bf.w);
                av[i]=t;
                if (cg==0){   // residual: ea += ea_new (one writer per row)
                    float4 evv = *(const float4*)(ea + (size_t)r*K + k4*4);
                    evv.x+=t.x; evv.y+=t.y; evv.z+=t.z; evv.w+=t.w;
                    *(float4*)(ea + (size_t)r*K + k4*4) = evv;
                }
            } else av[i]=make_float4(0.f,0.f,0.f,0.f);
        }
        const float* wp = em_w + (size_t)k4*4*C + c0;
        #pragma unroll
        for (int kk=0;kk<4;++kk){
            float4 wa = *(const float4*)(wp + kk*C);
            float4 wb = *(const float4*)(wp + kk*C + 4);
            #pragma unroll
            for (int i=0;i<4;++i){
                float aval = (kk==0)?av[i].x:(kk==1)?av[i].y:(kk==2)?av[i].z:av[i].w;
                acc[i][0]=fmaf(aval,wa.x,acc[i][0]);
                acc[i][1]=fmaf(aval,wa.y,acc[i][1]);
                acc[i][2]=fmaf(aval,wa.z,acc[i][2]);
                acc[i][3]=fmaf(aval,wa.w,acc[i][3]);
                acc[i][4]=fmaf(aval,wb.x,acc[i][4]);
                acc[i][5]=fmaf(aval,wb.y,acc[i][5]);
                acc[i][6]=fmaf(aval,wb.z,acc[i][6]);
                acc[i][7]=fmaf(aval,wb.w,acc[i][7]);
            }
        }
    }
    float mb[8];
    #pragma unroll
    for (int u=0;u<8;++u) mb[u]=em_b[c0+u];
    #pragma unroll
    for (int i=0;i<4;++i){
        int r=r0+i;
        if (r<R){
            int rj=row_idx[r];
            int p = pos[r];
            f8 sm = load8(smp + (size_t)rj*C + c0);
            float4 o0 = make_float4(acc[i][0]+mb[0]+sm.v[0], acc[i][1]+mb[1]+sm.v[1],
                                    acc[i][2]+mb[2]+sm.v[2], acc[i][3]+mb[3]+sm.v[3]);
            float4 o1 = make_float4(acc[i][4]+mb[4]+sm.v[4], acc[i][5]+mb[5]+sm.v[5],
                                    acc[i][6]+mb[6]+sm.v[6], acc[i][7]+mb[7]+sm.v[7]);
            *(float4*)(msgs + (size_t)p*C + c0)     = o0;
            *(float4*)(msgs + (size_t)p*C + c0 + 4) = o1;
        }
    }
}

// ================ CSR gather: agg[n] = sum of msg rows; + silu stats =======
__global__ __launch_bounds__(256) void gather_stats_kernel(
    const float* __restrict__ msgs, const int* __restrict__ rowptr,
    float* __restrict__ agg, float* __restrict__ stat_sum, float* __restrict__ stat_sq,
    int N)
{
    __shared__ float ssum[128], ssq[128];
    if (threadIdx.x < 128){ ssum[threadIdx.x]=0.f; ssq[threadIdx.x]=0.f; }
    __syncthreads();
    const int lane = threadIdx.x & 31, grp = threadIdx.x >> 5;
    const int c0 = lane*4;
    float ls[4]={0.f,0.f,0.f,0.f}, lq[4]={0.f,0.f,0.f,0.f};
    for (int n = blockIdx.x*8 + grp; n < N; n += gridDim.x*8){
        int s = rowptr[n], e = rowptr[n+1];
        float a0=0.f,a1=0.f,a2=0.f,a3=0.f;
        for (int i=s;i<e;++i){
            float4 v = *(const float4*)(msgs + (size_t)i*128 + c0);
            a0+=v.x; a1+=v.y; a2+=v.z; a3+=v.w;
        }
        *(float4*)(agg + (size_t)n*128 + c0) = make_float4(a0,a1,a2,a3);
        float t;
        t=dsilu(a0); ls[0]+=t; lq[0]+=t*t;
        t=dsilu(a1); ls[1]+=t; lq[1]+=t*t;
        t=dsilu(a2); ls[2]+=t; lq[2]+=t*t;
        t=dsilu(a3); ls[3]+=t; lq[3]+=t*t;
    }
    #pragma unroll
    for (int j=0;j<4;++j){ atomicAdd(&ssum[c0+j], ls[j]); atomicAdd(&ssq[c0+j], lq[j]); }
    __syncthreads();
    if (threadIdx.x < 128){
        atomicAdd(&stat_sum[threadIdx.x], ssum[threadIdx.x]);
        atomicAdd(&stat_sq[threadIdx.x],  ssq[threadIdx.x]);
    }
}

// x += silu(agg)*A + B
__global__ __launch_bounds__(256) void node_apply_kernel(float* __restrict__ x,
    const float* __restrict__ agg,
    const float* __restrict__ A, const float* __restrict__ B, int total4)
{
    __shared__ float sA[128], sB[128];
    if (threadIdx.x<128){ sA[threadIdx.x]=A[threadIdx.x]; sB[threadIdx.x]=B[threadIdx.x]; }
    __syncthreads();
    for (int i = blockIdx.x*256+threadIdx.x; i < total4; i += gridDim.x*256){
        int c0 = (i*4) & 127;
        float4 v  = *(const float4*)(agg + (size_t)i*4);
        float4 xv = *(const float4*)(x   + (size_t)i*4);
        xv.x += fmaf(dsilu(v.x), sA[c0],   sB[c0]);
        xv.y += fmaf(dsilu(v.y), sA[c0+1], sB[c0+1]);
        xv.z += fmaf(dsilu(v.z), sA[c0+2], sB[c0+2]);
        xv.w += fmaf(dsilu(v.w), sA[c0+3], sB[c0+3]);
        *(float4*)(x + (size_t)i*4) = xv;
    }
}

__global__ __launch_bounds__(256) void pool_kernel(const float* __restrict__ h,
    const int* __restrict__ batch, float* __restrict__ pooled, float* __restrict__ cnt)
{
    const int total = NN*32;
    for (int i = blockIdx.x*256+threadIdx.x; i < total; i += gridDim.x*256){
        int n = i >> 5, c0 = (i&31)*4;
        int b = batch[n];
        float4 v = *(const float4*)(h + (size_t)n*128 + c0);
        atomicAdd(&pooled[b*128+c0],   v.x);
        atomicAdd(&pooled[b*128+c0+1], v.y);
        atomicAdd(&pooled[b*128+c0+2], v.z);
        atomicAdd(&pooled[b*128+c0+3], v.w);
        if (c0==0) atomicAdd(&cnt[b], 1.f);
    }
}

__global__ __launch_bounds__(128) void mlp_kernel(const float* __restrict__ pooled,
    const float* __restrict__ cnt,
    const float* __restrict__ W1, const float* __restrict__ b1,
    const float* __restrict__ W2, const float* __restrict__ b2,
    const float* __restrict__ W3, const float* __restrict__ b3,
    float* __restrict__ out)
{
    __shared__ float p[128], o1[128], red[64];
    int g = blockIdx.x, t = threadIdx.x;
    float c = fmaxf(cnt[g], 1.0f);
    p[t] = pooled[g*128+t] / c;
    __syncthreads();
    float acc = b1[t];
    for (int k=0;k<128;++k) acc = fmaf(p[k], W1[k*128+t], acc);
    o1[t] = dsilu(acc);
    __syncthreads();
    if (t < 64){
        float a2 = b2[t];
        for (int k=0;k<128;++k) a2 = fmaf(o1[k], W2[k*64+t], a2);
        red[t] = dsilu(a2) * W3[t];
    }
    __syncthreads();
    for (int s2=32; s2>0; s2>>=1){
        if (t < s2) red[t] += red[t+s2];
        __syncthreads();
    }
    if (t==0) out[g] = red[0] + b3[0];
}

// ---------------------------------------------------------------------------
extern "C" void kernel_launch(void* const* d_in, const int* in_sizes, int n_in,
                              void* d_out, int out_size, void* d_ws, size_t ws_size,
                              hipStream_t stream)
{
    (void)in_sizes; (void)n_in; (void)out_size; (void)d_ws; (void)ws_size;

    const float* x_in      = (const float*)d_in[0];
    const int*   edge_index= (const int*)d_in[1];
    const float* edge_attr = (const float*)d_in[2];
    const int*   line_index= (const int*)d_in[3];
    const float* line_attr = (const float*)d_in[4];
    const int*   batch     = (const int*)d_in[5];
    const float* W_ae=(const float*)d_in[6];  const float* b_ae=(const float*)d_in[7];
    const float* W_ee=(const float*)d_in[8];  const float* b_ee=(const float*)d_in[9];
    const float* W_ng=(const float*)d_in[10]; const float* b_ng=(const float*)d_in[11];
    const float* W1=(const float*)d_in[12];   const float* b1=(const float*)d_in[13];
    const float* W2=(const float*)d_in[14];   const float* b2=(const float*)d_in[15];
    const float* W3=(const float*)d_in[16];   const float* b3=(const float*)d_in[17];
    const float* P[28];
    for (int i=0;i<28;++i) P[i] = (const float*)d_in[18+i];
    const float* const* LCQ = P;        // lc_* in _P order
    const float* const* ACQ = P + 14;   // ac_*

    float* ws = nullptr;
    hipGetSymbolAddress((void**)&ws, HIP_SYMBOL(g_ws));
    float* h     = ws;                        // [NN,128]
    float* e     = ws + 2560000;              // [NE,128]
    float* a     = ws + 33280000;             // [NL,32]
    float* z     = ws + 48640000;             // [NE,128] (>= NL*32)
    float* sgp   = ws + 79360000;             // [NE,32]  (>= NN*128)
    float* dgp   = ws + 87040000;             // [NE,32]
    float* smp   = ws + 94720000;             // [NE,128] (>= NN*128)
    float* agg   = ws + 125440000;            // [NE,128] (>= NN*128)
    float* stats = ws + 156160000;            // 1024
    float* pooled= stats + 1024;              // [NB,128]+NB
    float* cnt   = pooled + NB*128;
    float* msgs  = ws + 156180000;            // [NL,128] (>= NE*128)
    int*   iws   = (int*)(ws + 217620000);
    int* rowptr_ac = iws;                     // NN+1
    int* offs_ac   = iws + 20001;             // NN
    int* rowptr_lc = iws + 40001;             // NE+1
    int* offs_lc   = iws + 280002;            // NE
    int* pos_ac    = iws + 520002;            // NE
    int* pos_lc    = iws + 760002;            // NL
    int* partials  = iws + 1240002;           // <=1024

    const int* row  = edge_index;
    const int* col  = edge_index + NE;
    const int* lrow = line_index;
    const int* lcol = line_index + NL;

    // ---- CSR build (both graphs), once per launch
    auto build_csr = [&](const int* idx, int N, int E, int* rowptr, int* offs, int* pos){
        hipMemsetAsync(offs, 0, (size_t)N*sizeof(int), stream);
        hist_kernel<<<256,256,0,stream>>>(idx, offs, E);
        int nblk = cdiv(N,1024);
        scan1_kernel<<<nblk,256,0,stream>>>(offs, rowptr, partials, N);
        scan2_kernel<<<1,256,0,stream>>>(partials, nblk);
        scan3_kernel<<<cdiv(N,256),256,0,stream>>>(rowptr, partials, N, E);
        copy_i_kernel<<<256,256,0,stream>>>(rowptr, offs, N);
        pos_kernel<<<256,256,0,stream>>>(idx, offs, pos, E);
    };
    build_csr(col,  NN, NE, rowptr_ac, offs_ac, pos_ac);
    build_csr(lcol, NE, NL, rowptr_lc, offs_lc, pos_lc);

    // ---- embeddings
    gemm_sc_kernel<92,128><<<4096,256,0,stream>>>(x_in,      W_ae, b_ae, h, NN);
    gemm_sc_kernel<41,128><<<8192,256,0,stream>>>(edge_attr, W_ee, b_ee, e, NE);
    embed_a_kernel<<<2048,256,0,stream>>>(line_attr, W_ng, b_ng, a);

    auto run_egc = [&](float* xb, int Rx, float* eab, int Re, bool big,
                       const int* ridx, const int* cidx,
                       const int* rowptr, const int* pos,
                       const float* const* q, int li){
        const float* sg_w = q[0]  + (size_t)li*(big?16384:4096);
        const float* sg_b = q[1]  + li*(big?128:32);
        const float* dg_w = q[2]  + (size_t)li*(big?16384:4096);
        const float* dg_b = q[3]  + li*(big?128:32);
        const float* eg_w = q[4]  + (size_t)li*(big?16384:1024);
        const float* eg_b = q[5]  + li*(big?128:32);
        const float* bne_g= q[6]  + li*(big?128:32);
        const float* bne_b= q[7]  + li*(big?128:32);
        const float* sm_w = q[8]  + (size_t)li*16384;
        const float* sm_b = q[9]  + li*128;
        const float* em_w = q[10] + (size_t)li*(big?16384:4096);
        const float* em_b = q[11] + li*128;
        const float* bnn_g= q[12] + li*128;
        const float* bnn_b= q[13] + li*128;

        // node projections
        if (big){
            gemm_f4_kernel<128,128><<<cdiv(Rx,64),256,0,stream>>>(xb, sg_w, sg_b, sgp, Rx);
            gemm_f4_kernel<128,128><<<cdiv(Rx,64),256,0,stream>>>(xb, dg_w, dg_b, dgp, Rx);
        } else {
            gemm_f4_kernel<128,32><<<cdiv(Rx,256),256,0,stream>>>(xb, sg_w, sg_b, sgp, Rx);
            gemm_f4_kernel<128,32><<<cdiv(Rx,256),256,0,stream>>>(xb, dg_w, dg_b, dgp, Rx);
        }
        gemm_f4_kernel<128,128><<<cdiv(Rx,64),256,0,stream>>>(xb, sm_w, sm_b, smp, Rx);

        hipMemsetAsync(stats, 0, 1024*sizeof(float), stream);
        if (big)
            egc_gate_kernel<128><<<cdiv(Re,64),256,0,stream>>>(eab, sgp, dgp, ridx, cidx,
                eg_w, eg_b, z, stats, stats+128, Re);
        else
            egc_gate_kernel<32><<<cdiv(Re,256),256,0,stream>>>(eab, sgp, dgp, ridx, cidx,
                eg_w, eg_b, z, stats, stats+128, Re);
        bn_finalize_kernel<<<1,128,0,stream>>>(stats, stats+128, bne_g, bne_b,
            stats+256, stats+384, 1.0f/(float)Re, big?128:32);

        // message phase: sorted stores, no atomics
        if (big)
            egc_msg_kernel<128,128><<<cdiv(Re,64),256,0,stream>>>(z, eab, stats+256, stats+384,
                smp, ridx, pos, em_w, em_b, msgs, Re);
        else
            egc_msg_kernel<32,128><<<cdiv(Re,64),256,0,stream>>>(z, eab, stats+256, stats+384,
                smp, ridx, pos, em_w, em_b, msgs, Re);

        // CSR gather + fused node stats
        gather_stats_kernel<<<2048,256,0,stream>>>(msgs, rowptr, agg,
            stats+512, stats+640, Rx);
        bn_finalize_kernel<<<1,128,0,stream>>>(stats+512, stats+640, bnn_g, bnn_b,
            stats+768, stats+896, 1.0f/(float)Rx, 128);
        node_apply_kernel<<<2048,256,0,stream>>>(xb, agg, stats+768, stats+896, Rx*32);
    };

    for (int i=0;i<3;++i){
        run_egc(e, NE, a, NL, false, lrow, lcol, rowptr_lc, pos_lc, LCQ, i);  // line-graph
        run_egc(h, NN, e, NE, true,  row,  col,  rowptr_ac, pos_ac, ACQ, i);  // atom-graph
    }
    for (int i=3;i<6;++i)
        run_egc(h, NN, e, NE, true, row, col, rowptr_ac, pos_ac, ACQ, i);     // GCN layers

    // ---- pooling + MLP head
    hipMemsetAsync(pooled, 0, ((size_t)NB*128 + NB)*sizeof(float), stream);
    pool_kernel<<<1024,256,0,stream>>>(h, batch, pooled, cnt);
    mlp_kernel<<<NB,128,0,stream>>>(pooled, cnt, W1,b1,W2,b2,W3,b3, (float*)d_out);
}